// Round 1
// baseline (1334.986 us; speedup 1.0000x reference)
//
#include <hip/hip_runtime.h>
#include <stdint.h>

// Problem constants (fixed by the reference: B=8, C=8, H=512, W=512, STEPS=10)
constexpr int Wd = 512;
constexpr int Hd = 512;
constexpr int Cd = 8;
constexpr int Bd = 8;
constexpr int HW = Hd * Wd;        // 262144
constexpr int CHW = Cd * HW;       // 2097152
constexpr int BCHW = Bd * CHW;     // 16777216

// Threefry-2x32, 20 rounds — bit-exact replica of JAX's threefry2x32 cipher.
__host__ __device__ __forceinline__ void tf2x32(uint32_t k0, uint32_t k1,
                                                uint32_t x0, uint32_t x1,
                                                uint32_t& o0, uint32_t& o1) {
  const uint32_t k2 = k0 ^ k1 ^ 0x1BD11BDAu;
  x0 += k0; x1 += k1;
#define TFR(r) { x0 += x1; x1 = (x1 << (r)) | (x1 >> (32 - (r))); x1 ^= x0; }
  TFR(13) TFR(15) TFR(26) TFR(6)
  x0 += k1; x1 += k2 + 1u;
  TFR(17) TFR(29) TFR(16) TFR(24)
  x0 += k2; x1 += k0 + 2u;
  TFR(13) TFR(15) TFR(26) TFR(6)
  x0 += k0; x1 += k1 + 3u;
  TFR(17) TFR(29) TFR(16) TFR(24)
  x0 += k1; x1 += k2 + 4u;
  TFR(13) TFR(15) TFR(26) TFR(6)
  x0 += k2; x1 += k0 + 5u;
#undef TFR
  o0 = x0; o1 = x1;
}

// One parallel-Gibbs step. mode: 0 = first (acc=probs), 1 = mid (acc+=probs),
// 2 = last (out=(acc+probs)/10, write s_final as float).
__global__ __launch_bounds__(256) void gibbs_step(
    const float* __restrict__ unaries, const float* __restrict__ binaries,
    const int* __restrict__ s_in, int* __restrict__ s_out,
    float* __restrict__ acc, float* __restrict__ sfin,
    uint32_t k0, uint32_t k1, int mode) {
  __shared__ float sb[256];  // binaries [4][8][8]
  const int lt = threadIdx.x;
  sb[lt] = binaries[lt];
  __syncthreads();

  const int tid = blockIdx.x * 256 + lt;   // flat (b, r, c); c fastest -> coalesced
  const int c = tid & (Wd - 1);
  const int r = (tid >> 9) & (Hd - 1);
  const int b = tid >> 18;

  // Neighborhood order matches reference: (0,1),(1,0),(0,-1),(-1,0)
  const bool v0 = (c + 1) < Wd;
  const bool v1 = (r + 1) < Hd;
  const bool v2 = c > 0;
  const bool v3 = r > 0;
  const int n0 = v0 ? s_in[tid + 1] : 0;
  const int n1 = v1 ? s_in[tid + Wd] : 0;
  const int n2 = v2 ? s_in[tid - 1] : 0;
  const int n3 = v3 ? s_in[tid - Wd] : 0;

  const int ub = b * CHW + r * Wd + c;     // + ch*HW gives flat (b,ch,r,c)

  // Energies, same fp add order as reference (unary, then n=0..3).
  float e[8];
#pragma unroll
  for (int ch = 0; ch < 8; ++ch) {
    float v = unaries[ub + ch * HW];
    v += v0 ? sb[ch * 8 + n0] : 0.0f;
    v += v1 ? sb[64 + ch * 8 + n1] : 0.0f;
    v += v2 ? sb[128 + ch * 8 + n2] : 0.0f;
    v += v3 ? sb[192 + ch * 8 + n3] : 0.0f;
    e[ch] = v;
  }

  // Gumbel-argmax. Partitionable threefry bits: bits[j] = y0 ^ y1 of
  // cipher(key_t, (hi=0, lo=j)), j = flat index into (B,C,H,W).
  float zbest = 0.0f;
  int amax = 0;
#pragma unroll
  for (int ch = 0; ch < 8; ++ch) {
    uint32_t y0, y1;
    tf2x32(k0, k1, 0u, (uint32_t)(ub + ch * HW), y0, y1);
    const uint32_t bits = y0 ^ y1;
    // uniform in [tiny, 1): f32 at every step, like JAX
    const float f = __uint_as_float((bits >> 9) | 0x3F800000u) - 1.0f;
    const float U = (f > 0.0f) ? f : 1.17549435082228751e-38f;
    const float l1 = (float)log((double)U);       // f32-rounded inner log
    const float gum = -(float)log((double)(-l1)); // f32-rounded outer log
    const float z = -e[ch] + gum;
    if (ch == 0 || z > zbest) { zbest = z; amax = ch; }  // first-max tie rule
  }

  // softmax(-e) over classes, sequential sum order ch=0..7
  float m = -e[0];
#pragma unroll
  for (int ch = 1; ch < 8; ++ch) m = fmaxf(m, -e[ch]);
  float p[8];
  float s = 0.0f;
#pragma unroll
  for (int ch = 0; ch < 8; ++ch) {
    p[ch] = expf(-e[ch] - m);
    s += p[ch];
  }

  if (mode == 0) {
#pragma unroll
    for (int ch = 0; ch < 8; ++ch) acc[ub + ch * HW] = p[ch] / s;
  } else if (mode == 1) {
#pragma unroll
    for (int ch = 0; ch < 8; ++ch) acc[ub + ch * HW] += p[ch] / s;
  } else {
#pragma unroll
    for (int ch = 0; ch < 8; ++ch) {
      const int ix = ub + ch * HW;
      acc[ix] = (acc[ix] + p[ch] / s) / 10.0f;
    }
  }

  if (mode != 2) s_out[tid] = amax;
  else sfin[tid] = (float)amax;   // output dtype is f32; labels written as floats
}

extern "C" void kernel_launch(void* const* d_in, const int* in_sizes, int n_in,
                              void* d_out, int out_size, void* d_ws, size_t ws_size,
                              hipStream_t stream) {
  const float* unaries  = (const float*)d_in[0];
  const float* binaries = (const float*)d_in[1];
  const int*   sample0  = (const int*)d_in[2];
  // d_in[3] is sample_steps (=10, fixed by the reference) — on device, hard-coded.

  float* acc  = (float*)d_out;      // [B,C,H,W] marginal accumulator lives in d_out
  float* sfin = acc + BCHW;         // s_final (as floats) tail of d_out
  int* bufA = (int*)d_ws;           // 8 MB ping buffer
  int* bufB = (int*)sfin;           // pong buffer aliases the tail; overwritten
                                    // with floats only at the final step

  for (int t = 0; t < 10; ++t) {
    // Partitionable split: keys[t] = threefry2x32((0,42), (0,t)) — both words.
    uint32_t kA, kB;
    tf2x32(0u, 42u, 0u, (uint32_t)t, kA, kB);
    const int* sin = (t == 0) ? sample0 : ((t & 1) ? bufA : bufB);
    int* sout = (t & 1) ? bufB : bufA;
    const int mode = (t == 0) ? 0 : ((t == 9) ? 2 : 1);
    gibbs_step<<<dim3(BCHW / Cd / 256), dim3(256), 0, stream>>>(
        unaries, binaries, sin, sout, acc, sfin, kA, kB, mode);
  }
}

// Round 2
// 730.261 us; speedup vs baseline: 1.8281x; 1.8281x over previous
//
#include <hip/hip_runtime.h>
#include <stdint.h>
#include <math.h>

// Problem constants (fixed by the reference: B=8, C=8, H=512, W=512, STEPS=10)
constexpr int Wd = 512;
constexpr int Hd = 512;
constexpr int Cd = 8;
constexpr int Bd = 8;
constexpr int HW = Hd * Wd;        // 262144
constexpr int CHW = Cd * HW;       // 2097152
constexpr int BCHW = Bd * CHW;     // 16777216

// Threefry-2x32, 20 rounds — bit-exact replica of JAX's threefry2x32 cipher.
__host__ __device__ __forceinline__ void tf2x32(uint32_t k0, uint32_t k1,
                                                uint32_t x0, uint32_t x1,
                                                uint32_t& o0, uint32_t& o1) {
  const uint32_t k2 = k0 ^ k1 ^ 0x1BD11BDAu;
  x0 += k0; x1 += k1;
#define TFR(r) { x0 += x1; x1 = (x1 << (r)) | (x1 >> (32 - (r))); x1 ^= x0; }
  TFR(13) TFR(15) TFR(26) TFR(6)
  x0 += k1; x1 += k2 + 1u;
  TFR(17) TFR(29) TFR(16) TFR(24)
  x0 += k2; x1 += k0 + 2u;
  TFR(13) TFR(15) TFR(26) TFR(6)
  x0 += k0; x1 += k1 + 3u;
  TFR(17) TFR(29) TFR(16) TFR(24)
  x0 += k1; x1 += k2 + 4u;
  TFR(13) TFR(15) TFR(26) TFR(6)
  x0 += k2; x1 += k0 + 5u;
#undef TFR
  o0 = x0; o1 = x1;
}

// One parallel-Gibbs step. mode: 0 = first (acc=probs), 1 = mid (acc+=probs),
// 2 = last (out=(acc+probs)/10, write s_final as float).
__global__ __launch_bounds__(256) void gibbs_step(
    const float* __restrict__ unaries, const float* __restrict__ binaries,
    const int* __restrict__ s_in, int* __restrict__ s_out,
    float* __restrict__ acc, float* __restrict__ sfin,
    uint32_t k0, uint32_t k1, int mode) {
  __shared__ float sb[256];  // binaries [4][8][8]
  const int lt = threadIdx.x;
  sb[lt] = binaries[lt];
  __syncthreads();

  const int tid = blockIdx.x * 256 + lt;   // flat (b, r, c); c fastest -> coalesced
  const int c = tid & (Wd - 1);
  const int r = (tid >> 9) & (Hd - 1);
  const int b = tid >> 18;

  // Neighborhood order matches reference: (0,1),(1,0),(0,-1),(-1,0)
  const bool v0 = (c + 1) < Wd;
  const bool v1 = (r + 1) < Hd;
  const bool v2 = c > 0;
  const bool v3 = r > 0;
  const int n0 = v0 ? s_in[tid + 1] : 0;
  const int n1 = v1 ? s_in[tid + Wd] : 0;
  const int n2 = v2 ? s_in[tid - 1] : 0;
  const int n3 = v3 ? s_in[tid - Wd] : 0;

  const int ub = b * CHW + r * Wd + c;     // + ch*HW gives flat (b,ch,r,c)

  // Energies, same fp add order as reference (unary, then n=0..3).
  float e[8];
#pragma unroll
  for (int ch = 0; ch < 8; ++ch) {
    float v = unaries[ub + ch * HW];
    v += v0 ? sb[ch * 8 + n0] : 0.0f;
    v += v1 ? sb[64 + ch * 8 + n1] : 0.0f;
    v += v2 ? sb[128 + ch * 8 + n2] : 0.0f;
    v += v3 ? sb[192 + ch * 8 + n3] : 0.0f;
    e[ch] = v;
  }

  // Gumbel-argmax. Partitionable threefry bits: bits[j] = y0 ^ y1 of
  // cipher(key_t, (hi=0, lo=j)), j = flat index into (B,C,H,W).
  // Logs in f32 (OCML logf, <=1 ulp): trajectory-flip probability per draw
  // ~1e-7 * near-tie density -> expected <1 flip per full run.
  float zbest = 0.0f;
  int amax = 0;
#pragma unroll
  for (int ch = 0; ch < 8; ++ch) {
    uint32_t y0, y1;
    tf2x32(k0, k1, 0u, (uint32_t)(ub + ch * HW), y0, y1);
    const uint32_t bits = y0 ^ y1;
    // uniform in [tiny, 1): f32 at every step, like JAX
    const float f = __uint_as_float((bits >> 9) | 0x3F800000u) - 1.0f;
    const float U = (f > 0.0f) ? f : 1.17549435082228751e-38f;
    const float l1 = logf(U);
    const float gum = -logf(-l1);
    const float z = -e[ch] + gum;
    if (ch == 0 || z > zbest) { zbest = z; amax = ch; }  // first-max tie rule
  }

  // softmax(-e) over classes, sequential sum order ch=0..7.
  // Probs never feed back into the trajectory: fast exp + rcp are safe
  // (tolerance here is the 0.07 np-vs-f32 gap, not ulps).
  float m = -e[0];
#pragma unroll
  for (int ch = 1; ch < 8; ++ch) m = fmaxf(m, -e[ch]);
  float p[8];
  float s = 0.0f;
#pragma unroll
  for (int ch = 0; ch < 8; ++ch) {
    p[ch] = __expf(-e[ch] - m);
    s += p[ch];
  }
  const float inv = 1.0f / s;   // one divide instead of eight

  if (mode == 0) {
#pragma unroll
    for (int ch = 0; ch < 8; ++ch) acc[ub + ch * HW] = p[ch] * inv;
  } else if (mode == 1) {
#pragma unroll
    for (int ch = 0; ch < 8; ++ch) acc[ub + ch * HW] += p[ch] * inv;
  } else {
#pragma unroll
    for (int ch = 0; ch < 8; ++ch) {
      const int ix = ub + ch * HW;
      acc[ix] = (acc[ix] + p[ch] * inv) * 0.1f;
    }
  }

  if (mode != 2) s_out[tid] = amax;
  else sfin[tid] = (float)amax;   // output dtype is f32; labels written as floats
}

extern "C" void kernel_launch(void* const* d_in, const int* in_sizes, int n_in,
                              void* d_out, int out_size, void* d_ws, size_t ws_size,
                              hipStream_t stream) {
  const float* unaries  = (const float*)d_in[0];
  const float* binaries = (const float*)d_in[1];
  const int*   sample0  = (const int*)d_in[2];
  // d_in[3] is sample_steps (=10, fixed by the reference) — on device, hard-coded.

  float* acc  = (float*)d_out;      // [B,C,H,W] marginal accumulator lives in d_out
  float* sfin = acc + BCHW;         // s_final (as floats) tail of d_out
  int* bufA = (int*)d_ws;           // 8 MB ping buffer
  int* bufB = (int*)sfin;           // pong buffer aliases the tail; overwritten
                                    // with floats only at the final step

  for (int t = 0; t < 10; ++t) {
    // Partitionable split: keys[t] = threefry2x32((0,42), (0,t)) — both words.
    uint32_t kA, kB;
    tf2x32(0u, 42u, 0u, (uint32_t)t, kA, kB);
    const int* sin = (t == 0) ? sample0 : ((t & 1) ? bufA : bufB);
    int* sout = (t & 1) ? bufB : bufA;
    const int mode = (t == 0) ? 0 : ((t == 9) ? 2 : 1);
    gibbs_step<<<dim3(BCHW / Cd / 256), dim3(256), 0, stream>>>(
        unaries, binaries, sin, sout, acc, sfin, kA, kB, mode);
  }
}